// Round 3
// baseline (98.746 us; speedup 1.0000x reference)
//
#include <hip/hip_runtime.h>
#include <hip/hip_bf16.h>

// Problem constants
#define BDIM 8
#define CIN 32
#define COUT 32
#define WDIM 128
#define JDIM 16384           // 128*128
#define SDIM 1024
#define PARTS 32             // gather parts per batch (= COUT, so part == o)
#define SPP (SDIM / PARTS)   // 32 samples per part
#define TAG 0x5ca1ab1e       // != 0xAAAAAAAA poison

// ws layout:
//   floats [0 .. 32*8*96)   partials[part][b][i*3 + {P,Q0,Q1}]
//   ints   at byte 98304    flags[part][b]  (32*8)

// ---------------------------------------------------------------------------
// Single fused kernel. grid = 256 blocks (one per (b,o) output plane), 256 thr.
//  produce : block (b,o) gathers part o of batch b -> 96 partial sums + flag
//  sync    : spin on the 32 flags of batch b (agent scope; all blocks resident)
//  consume : reduce parts, contract with weight row o, stream 64KB plane out
// ---------------------------------------------------------------------------
__global__ __launch_bounds__(256) void k_fused(const float* __restrict__ v,
                                               const float* __restrict__ w,
                                               const int* __restrict__ idx,
                                               float* __restrict__ partials,
                                               int* __restrict__ flags,
                                               float* __restrict__ out) {
    const int bo = blockIdx.x;         // 0..255
    const int b  = bo >> 5;
    const int o  = bo & 31;
    const int part = o;                // producer role: part == o
    const int t  = threadIdx.x;
    const int i  = t & 31;             // input channel
    const int sg = t >> 5;             // 0..7 sample subgroup

    __shared__ float red[8][96];
    __shared__ float pq[96];
    __shared__ float coef[3];

    // ---------------- produce: gather SPP samples of (b, part) --------------
    {
        const float* vb = v + ((size_t)(b * CIN + i)) * JDIM;
        const float step = 2.0f / 127.0f;
        const int s0 = part * SPP + sg;
        const int j0 = idx[s0 +  0];
        const int j1 = idx[s0 +  8];
        const int j2 = idx[s0 + 16];
        const int j3 = idx[s0 + 24];
        const float v0 = vb[j0], v1 = vb[j1], v2 = vb[j2], v3 = vb[j3];

        const float x0 = -1.0f + (float)(j0 & (WDIM - 1)) * step;
        const float y0 = -1.0f + (float)(j0 >> 7) * step;
        const float x1 = -1.0f + (float)(j1 & (WDIM - 1)) * step;
        const float y1 = -1.0f + (float)(j1 >> 7) * step;
        const float x2 = -1.0f + (float)(j2 & (WDIM - 1)) * step;
        const float y2 = -1.0f + (float)(j2 >> 7) * step;
        const float x3 = -1.0f + (float)(j3 & (WDIM - 1)) * step;
        const float y3 = -1.0f + (float)(j3 >> 7) * step;

        red[sg][i * 3 + 0] = v0 + v1 + v2 + v3;
        red[sg][i * 3 + 1] = v0 * x0 + v1 * x1 + v2 * x2 + v3 * x3;
        red[sg][i * 3 + 2] = v0 * y0 + v1 * y1 + v2 * y2 + v3 * y3;
    }
    __syncthreads();

    if (t < 96) {
        float sum = 0.f;
#pragma unroll
        for (int g = 0; g < 8; ++g) sum += red[g][t];
        // agent-scope store: no reliance on L2 writeback for cross-XCD reads
        __hip_atomic_store(&partials[((size_t)(part * BDIM + b)) * 96 + t], sum,
                           __ATOMIC_RELAXED, __HIP_MEMORY_SCOPE_AGENT);
    }
    __syncthreads();
    if (t == 0) {
        __threadfence();   // order partial stores before flag
        __hip_atomic_store(&flags[part * BDIM + b], TAG,
                           __ATOMIC_RELEASE, __HIP_MEMORY_SCOPE_AGENT);
    }

    // ---------------- sync: wait for all 32 parts of batch b ----------------
    if (t < 32) {
        while (__hip_atomic_load(&flags[t * BDIM + b],
                                 __ATOMIC_RELAXED, __HIP_MEMORY_SCOPE_AGENT) != TAG) {
            __builtin_amdgcn_s_sleep(2);
        }
    }
    __syncthreads();
    __threadfence();       // acquire: no stale cached partials

    // ---------------- consume: reduce parts for batch b ---------------------
    if (t < 96) {
        float s = 0.f;
#pragma unroll
        for (int part2 = 0; part2 < PARTS; ++part2)
            s += __hip_atomic_load(&partials[((size_t)(part2 * BDIM + b)) * 96 + t],
                                   __ATOMIC_RELAXED, __HIP_MEMORY_SCOPE_AGENT);
        pq[t] = s;
    }
    __syncthreads();

    // contract with weight row o (lanes 0..63 of wave 0; halves duplicate)
    if (t < 64) {
        const int ci = t & 31;
        const float P  = pq[ci * 3 + 0];
        const float Q0 = pq[ci * 3 + 1];
        const float Q1 = pq[ci * 3 + 2];
        const float w0 = w[(o * CIN + ci) * 2 + 0];
        const float w1 = w[(o * CIN + ci) * 2 + 1];
        float t0 = P * w0;
        float t1 = P * w1;
        float kk = Q0 * w0 + Q1 * w1;
#pragma unroll
        for (int off = 16; off >= 1; off >>= 1) {
            t0 += __shfl_xor(t0, off);
            t1 += __shfl_xor(t1, off);
            kk += __shfl_xor(kk, off);
        }
        if (t == 0) {
            const float step = 2.0f / 127.0f;
            coef[0] = t0 * step;          // x slope
            coef[1] = t1 * step;          // y slope
            coef[2] = -(t0 + t1 + kk);    // constant (coords -1 offsets folded)
        }
    }
    __syncthreads();

    // ---------------- output: stream the 64KB plane --------------------------
    const float a  = coef[0];
    const float c  = coef[1];
    const float C0 = coef[2];
    float* outp = out + (size_t)bo * JDIM;

#pragma unroll
    for (int seg = 0; seg < 16; ++seg) {
        const int r = (seg * 256 + t) * 4;
        const int x = r & (WDIM - 1);     // r%4==0: float4 never splits a row
        const int y = r >> 7;
        const float base = (float)y * c + C0;
        float4 val;
        val.x = base + (float)(x + 0) * a;
        val.y = base + (float)(x + 1) * a;
        val.z = base + (float)(x + 2) * a;
        val.w = base + (float)(x + 3) * a;
        *reinterpret_cast<float4*>(outp + r) = val;
    }
}

// ---------------------------------------------------------------------------
extern "C" void kernel_launch(void* const* d_in, const int* in_sizes, int n_in,
                              void* d_out, int out_size, void* d_ws, size_t ws_size,
                              hipStream_t stream) {
    const float* v   = (const float*)d_in[0];
    const float* w   = (const float*)d_in[1];
    const int*   idx = (const int*)d_in[2];
    float* out = (float*)d_out;

    float* partials = (float*)d_ws;                       // 32*8*96 floats
    int*   flags    = (int*)((char*)d_ws + 98304);        // 32*8 ints

    k_fused<<<256, 256, 0, stream>>>(v, w, idx, partials, flags, out);
}